// Round 1
// baseline (646.239 us; speedup 1.0000x reference)
//
#include <hip/hip_runtime.h>

// HausdorffLoss (average): B=8, N=M=4096, C=128, fp32 in/out.
// d2 tile GEMM (quadratic form) + running row/col min via uint atomicMin,
// sqrt deferred to the final reduction (monotonic).
#define B_ 8
#define N_ 4096
#define M_ 4096
#define C_ 128

constexpr int BM = 64;
constexpr int BN = 64;
constexpr int BK = 32;

__global__ __launch_bounds__(256) void init_minbuf(unsigned int* buf, int n) {
    int i = blockIdx.x * 256 + threadIdx.x;
    if (i < n) buf[i] = 0x7F800000u;  // +inf
}

__global__ __launch_bounds__(256) void hausdorff_tile(
    const float* __restrict__ S1, const float* __restrict__ S2,
    unsigned int* __restrict__ rowmin, unsigned int* __restrict__ colmin) {

    __shared__ float As[BK][BM];   // [k][row] transposed for compute reads
    __shared__ float Bs[BK][BN];
    __shared__ float rsq[BM][8];
    __shared__ float csq[BN][8];
    __shared__ float red[64][17];

    const int b    = blockIdx.z;
    const int row0 = blockIdx.y * BM;
    const int col0 = blockIdx.x * BN;
    const int tid  = threadIdx.x;
    const int tx   = tid & 15;
    const int ty   = tid >> 4;

    const float* A  = S1 + ((size_t)b * N_ + row0) * C_;
    const float* Bp = S2 + ((size_t)b * M_ + col0) * C_;

    float acc[4][4] = {};
    float sqA0 = 0.f, sqA1 = 0.f, sqB0 = 0.f, sqB1 = 0.f;

    const int rA = tid >> 3;   // 0..31 ; owns rows rA and rA+32
    const int kq = tid & 7;    // float4 slot within the 32-float k-chunk

    for (int kk = 0; kk < C_; kk += BK) {
        float4 a0 = *(const float4*)(A  + (size_t)rA        * C_ + kk + kq * 4);
        float4 a1 = *(const float4*)(A  + (size_t)(rA + 32) * C_ + kk + kq * 4);
        float4 b0 = *(const float4*)(Bp + (size_t)rA        * C_ + kk + kq * 4);
        float4 b1 = *(const float4*)(Bp + (size_t)(rA + 32) * C_ + kk + kq * 4);

        sqA0 += a0.x*a0.x + a0.y*a0.y + a0.z*a0.z + a0.w*a0.w;
        sqA1 += a1.x*a1.x + a1.y*a1.y + a1.z*a1.z + a1.w*a1.w;
        sqB0 += b0.x*b0.x + b0.y*b0.y + b0.z*b0.z + b0.w*b0.w;
        sqB1 += b1.x*b1.x + b1.y*b1.y + b1.z*b1.z + b1.w*b1.w;

        As[kq*4+0][rA]      = a0.x; As[kq*4+1][rA]      = a0.y;
        As[kq*4+2][rA]      = a0.z; As[kq*4+3][rA]      = a0.w;
        As[kq*4+0][rA + 32] = a1.x; As[kq*4+1][rA + 32] = a1.y;
        As[kq*4+2][rA + 32] = a1.z; As[kq*4+3][rA + 32] = a1.w;
        Bs[kq*4+0][rA]      = b0.x; Bs[kq*4+1][rA]      = b0.y;
        Bs[kq*4+2][rA]      = b0.z; Bs[kq*4+3][rA]      = b0.w;
        Bs[kq*4+0][rA + 32] = b1.x; Bs[kq*4+1][rA + 32] = b1.y;
        Bs[kq*4+2][rA + 32] = b1.z; Bs[kq*4+3][rA + 32] = b1.w;

        __syncthreads();

        #pragma unroll
        for (int k = 0; k < BK; ++k) {
            float4 av = *(const float4*)&As[k][ty * 4];
            float4 bv = *(const float4*)&Bs[k][tx * 4];
            acc[0][0] += av.x * bv.x; acc[0][1] += av.x * bv.y;
            acc[0][2] += av.x * bv.z; acc[0][3] += av.x * bv.w;
            acc[1][0] += av.y * bv.x; acc[1][1] += av.y * bv.y;
            acc[1][2] += av.y * bv.z; acc[1][3] += av.y * bv.w;
            acc[2][0] += av.z * bv.x; acc[2][1] += av.z * bv.y;
            acc[2][2] += av.z * bv.z; acc[2][3] += av.z * bv.w;
            acc[3][0] += av.w * bv.x; acc[3][1] += av.w * bv.y;
            acc[3][2] += av.w * bv.z; acc[3][3] += av.w * bv.w;
        }
        __syncthreads();
    }

    rsq[rA][kq] = sqA0; rsq[rA + 32][kq] = sqA1;
    csq[rA][kq] = sqB0; csq[rA + 32][kq] = sqB1;
    __syncthreads();

    float sr[4], sc[4];
    #pragma unroll
    for (int i = 0; i < 4; ++i) {
        float s = 0.f;
        #pragma unroll
        for (int p = 0; p < 8; ++p) s += rsq[ty * 4 + i][p];
        sr[i] = s;
    }
    #pragma unroll
    for (int j = 0; j < 4; ++j) {
        float t = 0.f;
        #pragma unroll
        for (int p = 0; p < 8; ++p) t += csq[tx * 4 + j][p];
        sc[j] = t;
    }

    float rmin[4] = {1e30f, 1e30f, 1e30f, 1e30f};
    float cmin[4] = {1e30f, 1e30f, 1e30f, 1e30f};
    #pragma unroll
    for (int i = 0; i < 4; ++i)
        #pragma unroll
        for (int j = 0; j < 4; ++j) {
            float d2 = fmaxf(sr[i] + sc[j] - 2.f * acc[i][j], 0.f);
            rmin[i] = fminf(rmin[i], d2);
            cmin[j] = fminf(cmin[j], d2);
        }

    #pragma unroll
    for (int i = 0; i < 4; ++i) red[ty * 4 + i][tx] = rmin[i];
    __syncthreads();
    if (tid < 64) {
        float m = red[tid][0];
        #pragma unroll
        for (int p = 1; p < 16; ++p) m = fminf(m, red[tid][p]);
        atomicMin(&rowmin[(size_t)b * N_ + row0 + tid], __float_as_uint(m));
    }
    __syncthreads();

    #pragma unroll
    for (int j = 0; j < 4; ++j) red[tx * 4 + j][ty] = cmin[j];
    __syncthreads();
    if (tid < 64) {
        float m = red[tid][0];
        #pragma unroll
        for (int p = 1; p < 16; ++p) m = fminf(m, red[tid][p]);
        atomicMin(&colmin[(size_t)b * M_ + col0 + tid], __float_as_uint(m));
    }
}

__global__ __launch_bounds__(256) void hausdorff_reduce(
    const unsigned int* __restrict__ rowmin,
    const unsigned int* __restrict__ colmin, float* __restrict__ out) {
    __shared__ float warpsum[4];
    const int b = blockIdx.x;
    float s = 0.f;
    for (int i = threadIdx.x; i < N_; i += 256)
        s += sqrtf(fmaxf(__uint_as_float(rowmin[(size_t)b * N_ + i]), 0.f)) * (1.0f / N_);
    for (int i = threadIdx.x; i < M_; i += 256)
        s += sqrtf(fmaxf(__uint_as_float(colmin[(size_t)b * M_ + i]), 0.f)) * (1.0f / M_);
    #pragma unroll
    for (int off = 32; off > 0; off >>= 1) s += __shfl_down(s, off, 64);
    if ((threadIdx.x & 63) == 0) warpsum[threadIdx.x >> 6] = s;
    __syncthreads();
    if (threadIdx.x == 0)
        out[b] = warpsum[0] + warpsum[1] + warpsum[2] + warpsum[3];
}

extern "C" void kernel_launch(void* const* d_in, const int* in_sizes, int n_in,
                              void* d_out, int out_size, void* d_ws, size_t ws_size,
                              hipStream_t stream) {
    const float* s1 = (const float*)d_in[0];
    const float* s2 = (const float*)d_in[1];
    float* out = (float*)d_out;

    unsigned int* rowmin = (unsigned int*)d_ws;          // B*N uints (128 KB)
    unsigned int* colmin = rowmin + (size_t)B_ * N_;     // B*M uints (128 KB)

    const int ninit = B_ * (N_ + M_);
    init_minbuf<<<(ninit + 255) / 256, 256, 0, stream>>>(rowmin, ninit);

    dim3 grid(M_ / BN, N_ / BM, B_);
    hausdorff_tile<<<grid, 256, 0, stream>>>(s1, s2, rowmin, colmin);

    hausdorff_reduce<<<B_, 256, 0, stream>>>(rowmin, colmin, out);
}

// Round 2
// 258.825 us; speedup vs baseline: 2.4968x; 2.4968x over previous
//
#include <hip/hip_runtime.h>

// HausdorffLoss (average): B=8, N=M=4096, C=128, fp32 in/out.
// R2: inner product via bf16 MFMA (16x16x32), fp32 sq-norms, min-of-d2 with
// sqrt deferred to the final reduction. 128x128 tile / block, 4 waves.
#define B_ 8
#define N_ 4096
#define M_ 4096
#define C_ 128

typedef __attribute__((ext_vector_type(8))) short bf16x8;    // MFMA A/B frag
typedef __attribute__((ext_vector_type(4))) float floatx4;   // MFMA C/D frag
typedef __attribute__((ext_vector_type(8))) unsigned short ushort8;

// fp32 -> bf16 round-to-nearest-even
__device__ inline unsigned short f2bf(float x) {
    unsigned int u = __float_as_uint(x);
    u += 0x7FFFu + ((u >> 16) & 1u);
    return (unsigned short)(u >> 16);
}

__global__ __launch_bounds__(256) void init_minbuf(unsigned int* buf, int n) {
    int i = blockIdx.x * 256 + threadIdx.x;
    if (i < n) buf[i] = 0x7F800000u;  // +inf
}

__global__ __launch_bounds__(256) void hausdorff_mfma(
    const float* __restrict__ S1, const float* __restrict__ S2,
    unsigned int* __restrict__ rowmin, unsigned int* __restrict__ colmin) {

    // Unpadded 32-bf16 rows: fragment b128 reads at word (m*16 + quad*4) hit
    // each bank exactly 8x over the wave (the b128 floor) - no pad needed.
    __shared__ unsigned short A_lds[128 * 32];
    __shared__ unsigned short B_lds[128 * 32];
    __shared__ float asq_p[128][2];
    __shared__ float bsq_p[128][2];
    __shared__ float asq[128];
    __shared__ float bsq[128];

    const int b    = blockIdx.z;
    const int row0 = blockIdx.y * 128;
    const int col0 = blockIdx.x * 128;
    const int tid  = threadIdx.x;
    const int lane = tid & 63;
    const int w    = tid >> 6;        // wave 0..3
    const int lm   = lane & 15;       // MFMA lane-col
    const int quad = lane >> 4;       // MFMA quad
    const int qr   = (w >> 1) * 64;   // wave quadrant row offset
    const int qc   = (w & 1) * 64;    // wave quadrant col offset

    const float* Ag = S1 + ((size_t)b * N_ + row0) * C_;
    const float* Bg = S2 + ((size_t)b * M_ + col0) * C_;

    const int r = tid >> 1;           // staging row 0..127
    const int h = tid & 1;            // 16-float half of the 32-float chunk

    floatx4 acc[4][4] = {};
    float sqa = 0.f, sqb = 0.f;

    for (int kk = 0; kk < C_; kk += 32) {
        const float* pa = Ag + (size_t)r * C_ + kk + h * 16;
        const float* pb = Bg + (size_t)r * C_ + kk + h * 16;
        float4 a0 = *(const float4*)(pa + 0);
        float4 a1 = *(const float4*)(pa + 4);
        float4 a2 = *(const float4*)(pa + 8);
        float4 a3 = *(const float4*)(pa + 12);
        float4 b0 = *(const float4*)(pb + 0);
        float4 b1 = *(const float4*)(pb + 4);
        float4 b2 = *(const float4*)(pb + 8);
        float4 b3 = *(const float4*)(pb + 12);

        sqa += a0.x*a0.x + a0.y*a0.y + a0.z*a0.z + a0.w*a0.w
             + a1.x*a1.x + a1.y*a1.y + a1.z*a1.z + a1.w*a1.w
             + a2.x*a2.x + a2.y*a2.y + a2.z*a2.z + a2.w*a2.w
             + a3.x*a3.x + a3.y*a3.y + a3.z*a3.z + a3.w*a3.w;
        sqb += b0.x*b0.x + b0.y*b0.y + b0.z*b0.z + b0.w*b0.w
             + b1.x*b1.x + b1.y*b1.y + b1.z*b1.z + b1.w*b1.w
             + b2.x*b2.x + b2.y*b2.y + b2.z*b2.z + b2.w*b2.w
             + b3.x*b3.x + b3.y*b3.y + b3.z*b3.z + b3.w*b3.w;

        ushort8 oa0, oa1, ob0, ob1;
        oa0[0]=f2bf(a0.x); oa0[1]=f2bf(a0.y); oa0[2]=f2bf(a0.z); oa0[3]=f2bf(a0.w);
        oa0[4]=f2bf(a1.x); oa0[5]=f2bf(a1.y); oa0[6]=f2bf(a1.z); oa0[7]=f2bf(a1.w);
        oa1[0]=f2bf(a2.x); oa1[1]=f2bf(a2.y); oa1[2]=f2bf(a2.z); oa1[3]=f2bf(a2.w);
        oa1[4]=f2bf(a3.x); oa1[5]=f2bf(a3.y); oa1[6]=f2bf(a3.z); oa1[7]=f2bf(a3.w);
        ob0[0]=f2bf(b0.x); ob0[1]=f2bf(b0.y); ob0[2]=f2bf(b0.z); ob0[3]=f2bf(b0.w);
        ob0[4]=f2bf(b1.x); ob0[5]=f2bf(b1.y); ob0[6]=f2bf(b1.z); ob0[7]=f2bf(b1.w);
        ob1[0]=f2bf(b2.x); ob1[1]=f2bf(b2.y); ob1[2]=f2bf(b2.z); ob1[3]=f2bf(b2.w);
        ob1[4]=f2bf(b3.x); ob1[5]=f2bf(b3.y); ob1[6]=f2bf(b3.z); ob1[7]=f2bf(b3.w);

        __syncthreads();  // previous chunk's fragment reads done
        *(ushort8*)&A_lds[r * 32 + h * 16]     = oa0;
        *(ushort8*)&A_lds[r * 32 + h * 16 + 8] = oa1;
        *(ushort8*)&B_lds[r * 32 + h * 16]     = ob0;
        *(ushort8*)&B_lds[r * 32 + h * 16 + 8] = ob1;
        __syncthreads();

        bf16x8 af[4], bfr[4];
        #pragma unroll
        for (int i = 0; i < 4; ++i)
            af[i] = *(const bf16x8*)&A_lds[(qr + 16 * i + lm) * 32 + quad * 8];
        #pragma unroll
        for (int j = 0; j < 4; ++j)
            bfr[j] = *(const bf16x8*)&B_lds[(qc + 16 * j + lm) * 32 + quad * 8];
        #pragma unroll
        for (int i = 0; i < 4; ++i)
            #pragma unroll
            for (int j = 0; j < 4; ++j)
                acc[i][j] = __builtin_amdgcn_mfma_f32_16x16x32_bf16(
                    af[i], bfr[j], acc[i][j], 0, 0, 0);
    }

    // fp32 squared norms (exact, from the staging loads)
    asq_p[r][h] = sqa;
    bsq_p[r][h] = sqb;
    __syncthreads();
    if (tid < 128) asq[tid] = asq_p[tid][0] + asq_p[tid][1];
    else           bsq[tid - 128] = bsq_p[tid - 128][0] + bsq_p[tid - 128][1];
    __syncthreads();

    // Epilogue: d2 = asq[r] + bsq[c] - 2*inner, clamped; fold mins.
    // C/D layout: col = lm, row = quad*4 + reg (within each 16x16 tile).
    float rv[16];                       // per (i,reg): min over this lane's 4 cols
    float cv[4] = {1e30f, 1e30f, 1e30f, 1e30f};  // per j: min over 16 rows
    #pragma unroll
    for (int i = 0; i < 4; ++i) {
        #pragma unroll
        for (int reg = 0; reg < 4; ++reg) {
            const float sa = asq[qr + 16 * i + 4 * quad + reg];
            float m = 1e30f;
            #pragma unroll
            for (int j = 0; j < 4; ++j) {
                float d2 = fmaxf(sa + bsq[qc + 16 * j + lm]
                                 - 2.0f * acc[i][j][reg], 0.0f);
                m = fminf(m, d2);
                cv[j] = fminf(cv[j], d2);
            }
            rv[i * 4 + reg] = m;
        }
    }

    // Row mins: butterfly across the 16 lane-cols (quad preserved)
    #pragma unroll
    for (int s = 1; s < 16; s <<= 1)
        #pragma unroll
        for (int v = 0; v < 16; ++v)
            rv[v] = fminf(rv[v], __shfl_xor(rv[v], s, 64));
    if (lm == 0) {
        #pragma unroll
        for (int v = 0; v < 16; ++v) {
            int row = qr + 16 * (v >> 2) + 4 * quad + (v & 3);
            atomicMin(&rowmin[(size_t)b * N_ + row0 + row], __float_as_uint(rv[v]));
        }
    }

    // Col mins: butterfly across the 4 quads
    #pragma unroll
    for (int s = 16; s < 64; s <<= 1)
        #pragma unroll
        for (int j = 0; j < 4; ++j)
            cv[j] = fminf(cv[j], __shfl_xor(cv[j], s, 64));
    if (quad == 0) {
        #pragma unroll
        for (int j = 0; j < 4; ++j) {
            int col = qc + 16 * j + lm;
            atomicMin(&colmin[(size_t)b * M_ + col0 + col], __float_as_uint(cv[j]));
        }
    }
}

__global__ __launch_bounds__(256) void hausdorff_reduce(
    const unsigned int* __restrict__ rowmin,
    const unsigned int* __restrict__ colmin, float* __restrict__ out) {
    __shared__ float warpsum[4];
    const int b = blockIdx.x;
    float s = 0.f;
    for (int i = threadIdx.x; i < N_; i += 256)
        s += sqrtf(fmaxf(__uint_as_float(rowmin[(size_t)b * N_ + i]), 0.f)) * (1.0f / N_);
    for (int i = threadIdx.x; i < M_; i += 256)
        s += sqrtf(fmaxf(__uint_as_float(colmin[(size_t)b * M_ + i]), 0.f)) * (1.0f / M_);
    #pragma unroll
    for (int off = 32; off > 0; off >>= 1) s += __shfl_down(s, off, 64);
    if ((threadIdx.x & 63) == 0) warpsum[threadIdx.x >> 6] = s;
    __syncthreads();
    if (threadIdx.x == 0)
        out[b] = warpsum[0] + warpsum[1] + warpsum[2] + warpsum[3];
}

extern "C" void kernel_launch(void* const* d_in, const int* in_sizes, int n_in,
                              void* d_out, int out_size, void* d_ws, size_t ws_size,
                              hipStream_t stream) {
    const float* s1 = (const float*)d_in[0];
    const float* s2 = (const float*)d_in[1];
    float* out = (float*)d_out;

    unsigned int* rowmin = (unsigned int*)d_ws;          // B*N uints (128 KB)
    unsigned int* colmin = rowmin + (size_t)B_ * N_;     // B*M uints (128 KB)

    const int ninit = B_ * (N_ + M_);
    init_minbuf<<<(ninit + 255) / 256, 256, 0, stream>>>(rowmin, ninit);

    dim3 grid(M_ / 128, N_ / 128, B_);
    hausdorff_mfma<<<grid, 256, 0, stream>>>(s1, s2, rowmin, colmin);

    hausdorff_reduce<<<B_, 256, 0, stream>>>(rowmin, colmin, out);
}

// Round 3
// 216.844 us; speedup vs baseline: 2.9802x; 1.1936x over previous
//
#include <hip/hip_runtime.h>

// HausdorffLoss (average): B=8, N=M=4096, C=128, fp32 in/out.
// R3: full-K LDS tiles (XOR-swizzled, 64 KB), A staged once per 1024-col
// panel, register-prefetched B tiles, norms precomputed, min-of-d2 with
// sqrt deferred. MFMA 16x16x32 bf16.
#define B_ 8
#define N_ 4096
#define M_ 4096
#define C_ 128

typedef __attribute__((ext_vector_type(8))) short bf16x8;    // MFMA A/B frag
typedef __attribute__((ext_vector_type(4))) float floatx4;   // MFMA C/D frag
typedef __attribute__((ext_vector_type(8))) unsigned short ushort8;

// fp32 -> bf16 round-to-nearest-even
__device__ inline unsigned short f2bf(float x) {
    unsigned int u = __float_as_uint(x);
    u += 0x7FFFu + ((u >> 16) & 1u);
    return (unsigned short)(u >> 16);
}

// Fused prep: minbuf[i] = +inf AND norms[i] = ||row i||^2 (fp32 exact).
// i < B*N -> S1 row i ; else S2 row (i - B*N). Exactly 65536 threads.
__global__ __launch_bounds__(256) void prep_kernel(
    const float* __restrict__ S1, const float* __restrict__ S2,
    unsigned int* __restrict__ minbuf, float* __restrict__ norms) {
    const int i = blockIdx.x * 256 + threadIdx.x;
    minbuf[i] = 0x7F800000u;  // +inf
    const float* p = (i < B_ * N_) ? (S1 + (size_t)i * C_)
                                   : (S2 + (size_t)(i - B_ * N_) * C_);
    float s = 0.f;
    #pragma unroll
    for (int q = 0; q < C_ / 4; ++q) {
        float4 v = ((const float4*)p)[q];
        s += v.x * v.x + v.y * v.y + v.z * v.z + v.w * v.w;
    }
    norms[i] = s;
}

// Main: grid (N/128, M/1024, B). Block 256 thr / 4 waves, each wave a 64x64
// quadrant of the 128x128 product tile. LDS = A + B full-K bf16 = 64 KB.
// XOR swizzle: bf16 group g (8 elems) of row r lives at r*128 + (g^(r&15))*8.
// Reads and b128 writes both hit the 8-word/bank floor.
__global__ __launch_bounds__(256) void hausdorff_mfma(
    const float* __restrict__ S1, const float* __restrict__ S2,
    const float* __restrict__ asq_g, const float* __restrict__ bsq_g,
    unsigned int* __restrict__ rowmin, unsigned int* __restrict__ colmin) {

    __shared__ unsigned short A_lds[128 * 128];
    __shared__ unsigned short B_lds[128 * 128];

    const int b     = blockIdx.z;
    const int row0  = blockIdx.x * 128;
    const int panel = blockIdx.y;          // cols panel*1024 .. +1023
    const int tid   = threadIdx.x;
    const int lane  = tid & 63;
    const int w     = tid >> 6;
    const int lm    = lane & 15;
    const int quad  = lane >> 4;
    const int qr    = (w >> 1) * 64;
    const int qc    = (w & 1) * 64;

    const int r = tid >> 1;                // staging row 0..127
    const int h = tid & 1;                 // 64-float half
    const int sw = r & 15;

    // ---- stage A (full K) once ----
    {
        const float* pa = S1 + ((size_t)b * N_ + row0 + r) * C_ + h * 64;
        float4 av[16];
        #pragma unroll
        for (int q = 0; q < 16; ++q) av[q] = ((const float4*)pa)[q];
        #pragma unroll
        for (int j = 0; j < 8; ++j) {
            float4 v0 = av[2 * j], v1 = av[2 * j + 1];
            ushort8 o;
            o[0] = f2bf(v0.x); o[1] = f2bf(v0.y); o[2] = f2bf(v0.z); o[3] = f2bf(v0.w);
            o[4] = f2bf(v1.x); o[5] = f2bf(v1.y); o[6] = f2bf(v1.z); o[7] = f2bf(v1.w);
            *(ushort8*)&A_lds[r * 128 + (((h * 8 + j) ^ sw) * 8)] = o;
        }
    }

    // per-lane row norms for the 16 output rows this lane owns
    float sa[16];
    #pragma unroll
    for (int i = 0; i < 4; ++i)
        #pragma unroll
        for (int reg = 0; reg < 4; ++reg)
            sa[i * 4 + reg] =
                asq_g[(size_t)b * N_ + row0 + qr + 16 * i + 4 * quad + reg];

    // prefetch B tile 0 into registers
    float4 bv[16];
    {
        const float* pb = S2 + ((size_t)b * M_ + panel * 1024 + r) * C_ + h * 64;
        #pragma unroll
        for (int q = 0; q < 16; ++q) bv[q] = ((const float4*)pb)[q];
    }

    float rv[16];
    #pragma unroll
    for (int v = 0; v < 16; ++v) rv[v] = 1e30f;

    for (int it = 0; it < 8; ++it) {
        // convert current B registers to bf16 (register-only)
        ushort8 ob[8];
        #pragma unroll
        for (int j = 0; j < 8; ++j) {
            float4 v0 = bv[2 * j], v1 = bv[2 * j + 1];
            ob[j][0] = f2bf(v0.x); ob[j][1] = f2bf(v0.y);
            ob[j][2] = f2bf(v0.z); ob[j][3] = f2bf(v0.w);
            ob[j][4] = f2bf(v1.x); ob[j][5] = f2bf(v1.y);
            ob[j][6] = f2bf(v1.z); ob[j][7] = f2bf(v1.w);
        }

        __syncthreads();   // prev iter's MFMA reads of B_lds done (A visible too)
        #pragma unroll
        for (int j = 0; j < 8; ++j)
            *(ushort8*)&B_lds[r * 128 + (((h * 8 + j) ^ sw) * 8)] = ob[j];
        __syncthreads();   // staging visible

        // prefetch next B tile (overlaps the MFMA section below)
        if (it < 7) {
            const float* pb = S2 +
                ((size_t)b * M_ + panel * 1024 + (it + 1) * 128 + r) * C_ + h * 64;
            #pragma unroll
            for (int q = 0; q < 16; ++q) bv[q] = ((const float4*)pb)[q];
        }

        // col norms for this tile (L2/L3 scalar loads, latency hidden)
        float sb[4];
        #pragma unroll
        for (int j = 0; j < 4; ++j)
            sb[j] = bsq_g[(size_t)b * M_ + panel * 1024 + it * 128 + qc + 16 * j + lm];

        floatx4 acc[4][4] = {};
        #pragma unroll
        for (int c = 0; c < 4; ++c) {
            const int g = ((c * 4 + quad) ^ lm) * 8;  // swizzled group offset
            bf16x8 af[4], bfr[4];
            #pragma unroll
            for (int i = 0; i < 4; ++i)
                af[i] = *(const bf16x8*)&A_lds[(qr + 16 * i + lm) * 128 + g];
            #pragma unroll
            for (int j = 0; j < 4; ++j)
                bfr[j] = *(const bf16x8*)&B_lds[(qc + 16 * j + lm) * 128 + g];
            #pragma unroll
            for (int i = 0; i < 4; ++i)
                #pragma unroll
                for (int j = 0; j < 4; ++j)
                    acc[i][j] = __builtin_amdgcn_mfma_f32_16x16x32_bf16(
                        af[i], bfr[j], acc[i][j], 0, 0, 0);
        }

        // epilogue: d2 = sa + sb - 2*inner, clamp, fold mins
        float cv[4] = {1e30f, 1e30f, 1e30f, 1e30f};
        #pragma unroll
        for (int i = 0; i < 4; ++i)
            #pragma unroll
            for (int reg = 0; reg < 4; ++reg) {
                const float s = sa[i * 4 + reg];
                #pragma unroll
                for (int j = 0; j < 4; ++j) {
                    float d2 = fmaxf(s + sb[j] - 2.0f * acc[i][j][reg], 0.0f);
                    rv[i * 4 + reg] = fminf(rv[i * 4 + reg], d2);
                    cv[j] = fminf(cv[j], d2);
                }
            }

        // col mins: butterfly across the 4 quads, atomic per tile
        #pragma unroll
        for (int s = 16; s < 64; s <<= 1)
            #pragma unroll
            for (int j = 0; j < 4; ++j)
                cv[j] = fminf(cv[j], __shfl_xor(cv[j], s, 64));
        if (quad == 0) {
            #pragma unroll
            for (int j = 0; j < 4; ++j)
                atomicMin(&colmin[(size_t)b * M_ + panel * 1024 + it * 128 +
                                  qc + 16 * j + lm],
                          __float_as_uint(cv[j]));
        }
    }

    // row mins: folded over all 8 tiles; butterfly across the 16 lane-cols
    #pragma unroll
    for (int s = 1; s < 16; s <<= 1)
        #pragma unroll
        for (int v = 0; v < 16; ++v)
            rv[v] = fminf(rv[v], __shfl_xor(rv[v], s, 64));
    if (lm == 0) {
        #pragma unroll
        for (int v = 0; v < 16; ++v)
            atomicMin(&rowmin[(size_t)b * N_ + row0 + qr + 16 * (v >> 2) +
                              4 * quad + (v & 3)],
                      __float_as_uint(rv[v]));
    }
}

__global__ __launch_bounds__(256) void hausdorff_reduce(
    const unsigned int* __restrict__ rowmin,
    const unsigned int* __restrict__ colmin, float* __restrict__ out) {
    __shared__ float warpsum[4];
    const int b = blockIdx.x;
    float s = 0.f;
    for (int i = threadIdx.x; i < N_; i += 256)
        s += sqrtf(fmaxf(__uint_as_float(rowmin[(size_t)b * N_ + i]), 0.f)) * (1.0f / N_);
    for (int i = threadIdx.x; i < M_; i += 256)
        s += sqrtf(fmaxf(__uint_as_float(colmin[(size_t)b * M_ + i]), 0.f)) * (1.0f / M_);
    #pragma unroll
    for (int off = 32; off > 0; off >>= 1) s += __shfl_down(s, off, 64);
    if ((threadIdx.x & 63) == 0) warpsum[threadIdx.x >> 6] = s;
    __syncthreads();
    if (threadIdx.x == 0)
        out[b] = warpsum[0] + warpsum[1] + warpsum[2] + warpsum[3];
}

extern "C" void kernel_launch(void* const* d_in, const int* in_sizes, int n_in,
                              void* d_out, int out_size, void* d_ws, size_t ws_size,
                              hipStream_t stream) {
    const float* s1 = (const float*)d_in[0];
    const float* s2 = (const float*)d_in[1];
    float* out = (float*)d_out;

    // ws layout: rowmin (B*N u32) | colmin (B*M u32) | asq (B*N f32) | bsq (B*M f32)
    unsigned int* rowmin = (unsigned int*)d_ws;
    unsigned int* colmin = rowmin + (size_t)B_ * N_;
    float* norms = (float*)(colmin + (size_t)B_ * M_);
    float* asq = norms;                    // rows of S1
    float* bsq = norms + (size_t)B_ * N_;  // rows of S2

    prep_kernel<<<(B_ * (N_ + M_)) / 256, 256, 0, stream>>>(s1, s2, rowmin, norms);

    dim3 grid(N_ / 128, M_ / 1024, B_);
    hausdorff_mfma<<<grid, 256, 0, stream>>>(s1, s2, asq, bsq, rowmin, colmin);

    hausdorff_reduce<<<B_, 256, 0, stream>>>(rowmin, colmin, out);
}

// Round 5
// 132.899 us; speedup vs baseline: 4.8626x; 1.6316x over previous
//
#include <hip/hip_runtime.h>

// HausdorffLoss (average): B=8, N=M=4096, C=128, fp32 in/out.
// R5 = R4 with the prep-grid bug fixed ((BN+BM)/16 blocks, not /1024).
// prep: bf16-convert inputs into ws (XOR-swizzled k-groups) + norms + init.
// main: global_load_lds identity staging (zero staging VALU), A full-K +
// double-buffered 64-col B tiles (64 KB LDS, 1 barrier/iter), A-frags in
// registers, fused min-of-d2 epilogue (sqrt deferred). MFMA 16x16x32 bf16.
#define B_ 8
#define N_ 4096
#define M_ 4096
#define C_ 128
#define BN_ (B_ * N_)
#define BM_ (B_ * M_)

typedef __attribute__((ext_vector_type(8))) short bf16x8;    // MFMA A/B frag
typedef __attribute__((ext_vector_type(4))) float floatx4;   // MFMA C/D frag
typedef __attribute__((ext_vector_type(8))) unsigned short ushort8;

// fp32 -> bf16 round-to-nearest-even
__device__ __forceinline__ unsigned short f2bf(float x) {
    unsigned int u = __float_as_uint(x);
    u += 0x7FFFu + ((u >> 16) & 1u);
    return (unsigned short)(u >> 16);
}

// async global->LDS, 16 B per lane; LDS dest = wave-uniform base + lane*16
__device__ __forceinline__ void gl2lds16(const void* g, void* l) {
    __builtin_amdgcn_global_load_lds(
        (const __attribute__((address_space(1))) void*)g,
        (__attribute__((address_space(3))) void*)l, 16, 0, 0);
}

// ---------------------------------------------------------------------------
// Prep: bf16 convert (swizzled: ws[row][g ^ (row&15)] = src[row][g]),
// norms[row] = ||row||^2 (fp32), minbuf[row] = +inf, out zero-init.
// Wave handles 4 rows: lane = (row_in_4 : 2, k-group : 4).
// Grid = (BN_+BM_)/16 = 4096 blocks x 256 threads.
// ---------------------------------------------------------------------------
__global__ __launch_bounds__(256) void prep_kernel(
    const float* __restrict__ S1, const float* __restrict__ S2,
    unsigned int* __restrict__ minbuf, float* __restrict__ norms,
    unsigned short* __restrict__ bfA, unsigned short* __restrict__ bfB,
    float* __restrict__ out) {
    const int lane = threadIdx.x & 63;
    const int w    = threadIdx.x >> 6;
    const int gw   = blockIdx.x * 4 + w;
    const int r4   = lane >> 4;
    const int g4   = lane & 15;
    const int row  = gw * 4 + r4;          // 0 .. BN_+BM_-1

    const float* src = (row < BN_) ? S1 + (size_t)row * C_
                                   : S2 + (size_t)(row - BN_) * C_;
    float4 v0 = ((const float4*)src)[g4 * 2];
    float4 v1 = ((const float4*)src)[g4 * 2 + 1];

    float s = v0.x*v0.x + v0.y*v0.y + v0.z*v0.z + v0.w*v0.w
            + v1.x*v1.x + v1.y*v1.y + v1.z*v1.z + v1.w*v1.w;
    s += __shfl_xor(s, 1, 64);
    s += __shfl_xor(s, 2, 64);
    s += __shfl_xor(s, 4, 64);
    s += __shfl_xor(s, 8, 64);

    ushort8 o;
    o[0] = f2bf(v0.x); o[1] = f2bf(v0.y); o[2] = f2bf(v0.z); o[3] = f2bf(v0.w);
    o[4] = f2bf(v1.x); o[5] = f2bf(v1.y); o[6] = f2bf(v1.z); o[7] = f2bf(v1.w);

    unsigned short* dst = (row < BN_) ? bfA + (size_t)row * C_
                                      : bfB + (size_t)(row - BN_) * C_;
    *(ushort8*)&dst[(g4 ^ (row & 15)) * 8] = o;

    if (g4 == 0) { norms[row] = s; minbuf[row] = 0x7F800000u; }
    if (blockIdx.x == 0 && threadIdx.x < B_) out[threadIdx.x] = 0.f;
}

// ---------------------------------------------------------------------------
// Main: grid (N/128, M/1024, B). 4 waves; wave tile = 64 rows x 32 cols.
// LDS: A full-K (32 KB) + B double-buffered 64-col tiles (2 x 16 KB).
// ---------------------------------------------------------------------------
__global__ __launch_bounds__(256, 2) void hausdorff_mfma(
    const unsigned short* __restrict__ Abf, const unsigned short* __restrict__ Bbf,
    const float* __restrict__ asq_g, const float* __restrict__ bsq_g,
    unsigned int* __restrict__ rowmin, unsigned int* __restrict__ colmin) {

    __shared__ unsigned short A_lds[128 * 128];     // 32 KB
    __shared__ unsigned short B_lds[2][64 * 128];   // 2 x 16 KB

    const int b     = blockIdx.z;
    const int row0  = blockIdx.x * 128;
    const int panel = blockIdx.y;                   // cols panel*1024 ..
    const int tid   = threadIdx.x;
    const int lane  = tid & 63;
    const int w     = tid >> 6;
    const int lm    = lane & 15;
    const int quad  = lane >> 4;
    const int wrow  = (w >> 1) * 64;                // wave's row half
    const int qc    = (w & 1) * 32;                 // wave's col half (of 64)

    const unsigned short* Aws = Abf + ((size_t)b * N_ + row0) * C_;
    const unsigned short* Bws = Bbf + ((size_t)b * M_ + panel * 1024) * C_;

    // stage A (identity copy of pre-swizzled ws image)
    #pragma unroll
    for (int k = 0; k < 8; ++k) {
        const int off = w * 4096 + k * 512;         // ushorts
        gl2lds16(Aws + off + lane * 8, &A_lds[off]);
    }
    // stage B tile 0
    #pragma unroll
    for (int k = 0; k < 4; ++k) {
        const int off = w * 2048 + k * 512;
        gl2lds16(Bws + off + lane * 8, &B_lds[0][off]);
    }

    // row norms for this lane's 16 rows: wrow + 16i + 4*quad + reg
    float sa[16];
    #pragma unroll
    for (int i = 0; i < 4; ++i) {
        float4 t = *(const float4*)&asq_g[(size_t)b * N_ + row0 + wrow + 16 * i + 4 * quad];
        sa[4*i+0] = t.x; sa[4*i+1] = t.y; sa[4*i+2] = t.z; sa[4*i+3] = t.w;
    }

    float rv[16];
    #pragma unroll
    for (int v = 0; v < 16; ++v) rv[v] = 1e30f;

    __syncthreads();   // A + B0 staged

    // A fragments once (A_lds never rewritten)
    bf16x8 af[4][4];
    #pragma unroll
    for (int i = 0; i < 4; ++i)
        #pragma unroll
        for (int c = 0; c < 4; ++c)
            af[i][c] = *(const bf16x8*)
                &A_lds[(wrow + 16 * i + lm) * 128 + (((c * 4 + quad) ^ lm) * 8)];

    for (int it = 0; it < 16; ++it) {
        const int cur = it & 1;
        if (it < 15) {   // stage next tile into the other buffer
            const unsigned short* Bt = Bws + (size_t)(it + 1) * 64 * C_;
            #pragma unroll
            for (int k = 0; k < 4; ++k) {
                const int off = w * 2048 + k * 512;
                gl2lds16(Bt + off + lane * 8, &B_lds[cur ^ 1][off]);
            }
        }
        const int colbase = panel * 1024 + it * 64;
        const float sb0 = bsq_g[(size_t)b * M_ + colbase + qc + lm];
        const float sb1 = bsq_g[(size_t)b * M_ + colbase + qc + 16 + lm];

        bf16x8 bf[2][4];
        #pragma unroll
        for (int j = 0; j < 2; ++j)
            #pragma unroll
            for (int c = 0; c < 4; ++c)
                bf[j][c] = *(const bf16x8*)
                    &B_lds[cur][(qc + 16 * j + lm) * 128 + (((c * 4 + quad) ^ lm) * 8)];

        floatx4 acc[4][2] = {};
        #pragma unroll
        for (int c = 0; c < 4; ++c)
            #pragma unroll
            for (int i = 0; i < 4; ++i)
                #pragma unroll
                for (int j = 0; j < 2; ++j)
                    acc[i][j] = __builtin_amdgcn_mfma_f32_16x16x32_bf16(
                        af[i][c], bf[j][c], acc[i][j], 0, 0, 0);

        float cv0 = 1e30f, cv1 = 1e30f;
        #pragma unroll
        for (int i = 0; i < 4; ++i)
            #pragma unroll
            for (int reg = 0; reg < 4; ++reg) {
                const int v = 4 * i + reg;
                float d0 = fmaf(-2.0f, acc[i][0][reg], sa[v] + sb0);
                float d1 = fmaf(-2.0f, acc[i][1][reg], sa[v] + sb1);
                rv[v] = fminf(rv[v], fminf(d0, d1));   // -> v_min3
                cv0 = fminf(cv0, d0);
                cv1 = fminf(cv1, d1);
            }
        cv0 = fminf(cv0, __shfl_xor(cv0, 16, 64));
        cv0 = fminf(cv0, __shfl_xor(cv0, 32, 64));
        cv1 = fminf(cv1, __shfl_xor(cv1, 16, 64));
        cv1 = fminf(cv1, __shfl_xor(cv1, 32, 64));
        if (quad == 0) {
            atomicMin(&colmin[(size_t)b * M_ + colbase + qc + lm],
                      __float_as_uint(fmaxf(cv0, 0.f)));
            atomicMin(&colmin[(size_t)b * M_ + colbase + qc + 16 + lm],
                      __float_as_uint(fmaxf(cv1, 0.f)));
        }
        __syncthreads();   // protects cur buffer reuse + drains staged loads
    }

    #pragma unroll
    for (int s = 1; s < 16; s <<= 1)
        #pragma unroll
        for (int v = 0; v < 16; ++v)
            rv[v] = fminf(rv[v], __shfl_xor(rv[v], s, 64));
    if (lm == 0) {
        #pragma unroll
        for (int v = 0; v < 16; ++v)
            atomicMin(&rowmin[(size_t)b * N_ + row0 + wrow + 16 * (v >> 2) +
                              4 * quad + (v & 3)],
                      __float_as_uint(fmaxf(rv[v], 0.f)));
    }
}

// ---------------------------------------------------------------------------
// Reduce: 64 blocks (8 per batch), partial sums -> atomicAdd(out[b]).
// ---------------------------------------------------------------------------
__global__ __launch_bounds__(256) void hausdorff_reduce(
    const unsigned int* __restrict__ rowmin,
    const unsigned int* __restrict__ colmin, float* __restrict__ out) {
    __shared__ float ws4[4];
    const int b    = blockIdx.x >> 3;
    const int part = blockIdx.x & 7;
    const int base = part * 512;
    float s = 0.f;
    for (int i = base + threadIdx.x; i < base + 512; i += 256)
        s += sqrtf(fmaxf(__uint_as_float(rowmin[(size_t)b * N_ + i]), 0.f)) * (1.f / N_)
           + sqrtf(fmaxf(__uint_as_float(colmin[(size_t)b * M_ + i]), 0.f)) * (1.f / M_);
    #pragma unroll
    for (int off = 32; off > 0; off >>= 1) s += __shfl_down(s, off, 64);
    if ((threadIdx.x & 63) == 0) ws4[threadIdx.x >> 6] = s;
    __syncthreads();
    if (threadIdx.x == 0)
        atomicAdd(&out[b], ws4[0] + ws4[1] + ws4[2] + ws4[3]);
}

extern "C" void kernel_launch(void* const* d_in, const int* in_sizes, int n_in,
                              void* d_out, int out_size, void* d_ws, size_t ws_size,
                              hipStream_t stream) {
    const float* s1 = (const float*)d_in[0];
    const float* s2 = (const float*)d_in[1];
    float* out = (float*)d_out;

    // ws: rowmin(BN u32) | colmin(BM u32) | norms(BN+BM f32) | bfA | bfB
    unsigned int* rowmin = (unsigned int*)d_ws;
    unsigned int* colmin = rowmin + BN_;
    float* norms         = (float*)(colmin + BM_);
    unsigned short* bfA  = (unsigned short*)(norms + BN_ + BM_);
    unsigned short* bfB  = bfA + (size_t)BN_ * C_;

    // 16 rows per block -> 4096 blocks (R4 bug: divided by 1024, leaving
    // 98% of the ws image poisoned).
    prep_kernel<<<(BN_ + BM_) / 16, 256, 0, stream>>>(
        s1, s2, rowmin, norms, bfA, bfB, out);

    dim3 grid(N_ / 128, M_ / 1024, B_);
    hausdorff_mfma<<<grid, 256, 0, stream>>>(
        bfA, bfB, norms, norms + BN_, rowmin, colmin);

    hausdorff_reduce<<<B_ * 8, 256, 0, stream>>>(rowmin, colmin, out);
}